// Round 1
// baseline (1593.345 us; speedup 1.0000x reference)
//
#include <hip/hip_runtime.h>
#include <math.h>

#define BB    1024   // batch (G*P)
#define HDD   128    // h_dim
#define EE    64     // embedding dim
#define G4    512    // 4*HDD (gates)
#define SCN   32     // scenes
#define PED   32     // peds per scene
#define MLPD  1024   // mlp_dim / bottleneck
#define NSTEP 12

#define BN_SF 0.9999950000374997f  /* 1/sqrt(1+1e-5) */

__device__ __forceinline__ float sigm(float x) { return 1.0f / (1.0f + expf(-x)); }

// ---- once: u[c], v[c] for the rank-1 agent-type contribution to m1 ----
// at_emb = at0 * rowsum(Wp_at) + bp_at ; m1 pre-act = 0.05*h@Wm1h + at0*u + v
__global__ void k_uv(const float* __restrict__ Wp_at, const float* __restrict__ bp_at,
                     const float* __restrict__ Wm1, const float* __restrict__ bm1,
                     float* __restrict__ uv) {
    __shared__ float rw[EE];
    int t = threadIdx.x;  // 512
    if (t < EE) {
        float s = 0.f;
        for (int k = 0; k < 6; ++k) s += Wp_at[k * EE + t];
        rw[t] = s;
    }
    __syncthreads();
    float u = 0.f, v = 0.f;
    for (int e = 0; e < EE; ++e) {
        float w = Wm1[(HDD + e) * G4 + t];
        u += rw[e] * w;
        v += bp_at[e] * w;
    }
    uv[t]      = 0.05f * u;
    uv[G4 + t] = 0.05f * v + bm1[t];
}

// ---- once: di0 = last_pos_rel @ W_sp + b_sp ----
__global__ void k_di0(const float* __restrict__ lpr, const float* __restrict__ W_sp,
                      const float* __restrict__ b_sp, float* __restrict__ di) {
    int i = blockIdx.x * blockDim.x + threadIdx.x;  // BB*EE
    if (i >= BB * EE) return;
    int r = i >> 6, c = i & 63;
    di[i] = lpr[r * 2] * W_sp[c] + lpr[r * 2 + 1] * W_sp[EE + c] + b_sp[c];
}

// ---- per step: LSTM + rel + di_next + m1 (4 rows / block) ----
__global__ __launch_bounds__(512) void k_lstm(
    const float* __restrict__ W_ih, const float* __restrict__ W_hh,
    const float* __restrict__ b_ih, const float* __restrict__ b_hh,
    const float* __restrict__ W_h2p, const float* __restrict__ b_h2p,
    const float* __restrict__ W_sp, const float* __restrict__ b_sp,
    const float* __restrict__ Wm1, const float* __restrict__ at0,
    const float* __restrict__ uv,
    const float* __restrict__ hprev, float* __restrict__ cbuf,
    float* __restrict__ di, float* __restrict__ hA, float* __restrict__ m1,
    float* __restrict__ outrel) {
    __shared__ float sdi[4][EE];
    __shared__ float sh[4][HDD];
    __shared__ float sg[4][G4];
    __shared__ float shl[4][HDD];
    __shared__ float srel[4][2];
    int t = threadIdx.x;
    int row0 = blockIdx.x * 4;

    for (int i = t; i < 4 * EE; i += 512) sdi[i >> 6][i & 63] = di[row0 * EE + i];
    for (int i = t; i < 4 * HDD; i += 512) sh[i >> 7][i & 127] = hprev[row0 * HDD + i];
    __syncthreads();

    // gates, column t, 4 rows
    float acc[4];
    {
        float b = b_ih[t] + b_hh[t];
#pragma unroll
        for (int r = 0; r < 4; ++r) acc[r] = b;
    }
    for (int k = 0; k < EE; ++k) {
        float w = W_ih[k * G4 + t];
#pragma unroll
        for (int r = 0; r < 4; ++r) acc[r] += sdi[r][k] * w;
    }
    for (int k = 0; k < HDD; ++k) {
        float w = W_hh[k * G4 + t];
#pragma unroll
        for (int r = 0; r < 4; ++r) acc[r] += sh[r][k] * w;
    }
#pragma unroll
    for (int r = 0; r < 4; ++r) sg[r][t] = acc[r];
    __syncthreads();

    // LSTM pointwise: 4 rows x 128 cols = 512 items
    {
        int r = t >> 7, j = t & 127;
        int row = row0 + r;
        float gi = sg[r][j], gf = sg[r][j + HDD], gg = sg[r][j + 2 * HDD], go = sg[r][j + 3 * HDD];
        float cn = sigm(gf) * cbuf[row * HDD + j] + sigm(gi) * tanhf(gg);
        float hn = sigm(go) * tanhf(cn);
        cbuf[row * HDD + j] = cn;
        shl[r][j] = hn;
        hA[row * HDD + j] = hn;
    }
    __syncthreads();

    // rel = h @ W_h2p + b_h2p (8 threads)
    if (t < 8) {
        int r = t >> 1, d = t & 1;
        float s = b_h2p[d];
        for (int k = 0; k < HDD; ++k) s += shl[r][k] * W_h2p[k * 2 + d];
        srel[r][d] = s;
        outrel[(row0 + r) * 2 + d] = s;
    }
    __syncthreads();

    // di_next = rel @ W_sp + b_sp (256 threads)
    if (t < 256) {
        int r = t >> 6, cc = t & 63;
        di[(row0 + r) * EE + cc] = srel[r][0] * W_sp[cc] + srel[r][1] * W_sp[EE + cc] + b_sp[cc];
    }

    // m1 = relu(BN_S*(0.05*h@Wm1h + at0*u + v)), column t, 4 rows
    float a[4] = {0.f, 0.f, 0.f, 0.f};
    for (int k = 0; k < HDD; ++k) {
        float w = Wm1[k * G4 + t];
#pragma unroll
        for (int r = 0; r < 4; ++r) a[r] += shl[r][k] * w;
    }
    float uc = uv[t], vc = uv[G4 + t];
#pragma unroll
    for (int r = 0; r < 4; ++r) {
        float pre = 0.05f * a[r] + at0[row0 + r] * uc + vc;
        m1[(row0 + r) * G4 + t] = fmaxf(BN_SF * pre, 0.f);
    }
}

// ---- per step: m2 = m1 @ Wm2, per-scene max over 32 rows, bnrelu -> ph (32x1024) ----
// grid (8 coltiles, 32 scenes), 512 threads = 128 cols x 4 rowgroups(8 rows)
__global__ __launch_bounds__(512) void k_m2max(const float* __restrict__ Wm2,
                                               const float* __restrict__ bm2,
                                               const float* __restrict__ m1,
                                               float* __restrict__ ph) {
    __shared__ float sm1t[G4 * 36];  // transposed [k][row], pad 36 for alignment
    __shared__ float smax[128][4];
    int t = threadIdx.x;
    int ct = blockIdx.x, s = blockIdx.y;
    for (int i = t; i < PED * G4; i += 512) {
        int row = i >> 9, k = i & 511;
        sm1t[k * 36 + row] = m1[(s * PED) * G4 + i];
    }
    __syncthreads();
    int cl = t & 127, rg = t >> 7;
    int cc = ct * 128 + cl;
    const float* wp = Wm2 + cc;
    float acc[8] = {0.f, 0.f, 0.f, 0.f, 0.f, 0.f, 0.f, 0.f};
    for (int k = 0; k < G4; ++k) {
        const float* sp = &sm1t[k * 36 + rg * 8];
        float4 v0 = *(const float4*)(sp);
        float4 v1 = *(const float4*)(sp + 4);
        float w = wp[k * MLPD];
        acc[0] += v0.x * w; acc[1] += v0.y * w; acc[2] += v0.z * w; acc[3] += v0.w * w;
        acc[4] += v1.x * w; acc[5] += v1.y * w; acc[6] += v1.z * w; acc[7] += v1.w * w;
    }
    float mx = acc[0];
#pragma unroll
    for (int r = 1; r < 8; ++r) mx = fmaxf(mx, acc[r]);
    smax[cl][rg] = mx;
    __syncthreads();
    if (t < 128) {
        float m = fmaxf(fmaxf(smax[t][0], smax[t][1]), fmaxf(smax[t][2], smax[t][3]));
        ph[s * MLPD + ct * 128 + t] = fmaxf(BN_SF * (m + bm2[ct * 128 + t]), 0.f);
    }
}

// ---- per step: phW = ph @ Wd1[128:,:] + bd1 (32 x 1024) ----
// grid (16 coltiles(64), 4 rowtiles(8)), 512 threads = 64 cols x 8 rows
__global__ __launch_bounds__(512) void k_phw(const float* __restrict__ Wd1,
                                             const float* __restrict__ bd1,
                                             const float* __restrict__ ph,
                                             float* __restrict__ phW) {
    __shared__ float sph[8][MLPD];
    int t = threadIdx.x;
    int ct = blockIdx.x, rt = blockIdx.y;
    for (int i = t; i < 8 * MLPD; i += 512) sph[i >> 10][i & 1023] = ph[(rt * 8) * MLPD + i];
    __syncthreads();
    int cl = t & 63, r = t >> 6;
    int cc = ct * 64 + cl;
    const float* wp = Wd1 + HDD * MLPD + cc;
    float accv = bd1[cc];
    for (int k = 0; k < MLPD; ++k) accv += sph[r][k] * wp[k * MLPD];
    phW[(rt * 8 + r) * MLPD + cc] = accv;
}

// ---- per step: dh1 = relu(BN_S*(h@Wd1[:128,:] + phW[scene])) (1024x1024) ----
// grid (2 coltiles(512), 128 rowblocks(8)), 512 threads = col
__global__ __launch_bounds__(512) void k_dh1(const float* __restrict__ Wd1,
                                             const float* __restrict__ hA,
                                             const float* __restrict__ phW,
                                             float* __restrict__ dh1) {
    __shared__ float sh[8][HDD];
    int t = threadIdx.x;
    int ct = blockIdx.x, rb = blockIdx.y;
    int row0 = rb * 8;
    for (int i = t; i < 8 * HDD; i += 512) sh[i >> 7][i & 127] = hA[row0 * HDD + i];
    __syncthreads();
    int cc = ct * 512 + t;
    int s = row0 >> 5;
    float acc[8] = {0.f, 0.f, 0.f, 0.f, 0.f, 0.f, 0.f, 0.f};
    for (int k = 0; k < HDD; ++k) {
        float w = Wd1[k * MLPD + cc];
#pragma unroll
        for (int r = 0; r < 8; ++r) acc[r] += sh[r][k] * w;
    }
    float pw = phW[s * MLPD + cc];
#pragma unroll
    for (int r = 0; r < 8; ++r)
        dh1[(row0 + r) * MLPD + cc] = fmaxf(BN_SF * (acc[r] + pw), 0.f);
}

// ---- per step: h_next = relu(BN_S*(dh1 @ Wd2 + bd2)) (1024x128) ----
// grid 128 rowblocks(8), 1024 threads = 128 cols x 8 rows
__global__ __launch_bounds__(1024) void k_dh2(const float* __restrict__ Wd2,
                                              const float* __restrict__ bd2,
                                              const float* __restrict__ dh1,
                                              float* __restrict__ hB) {
    __shared__ float sd[8][MLPD];
    int t = threadIdx.x;
    int row0 = blockIdx.x * 8;
    for (int i = t; i < 8 * MLPD; i += 1024) sd[i >> 10][i & 1023] = dh1[row0 * MLPD + i];
    __syncthreads();
    int cl = t & 127, r = t >> 7;
    const float* wp = Wd2 + cl;
    float accv = 0.f;
    for (int k = 0; k < MLPD; ++k) accv += sd[r][k] * wp[k * HDD];
    hB[(row0 + r) * HDD + cl] = fmaxf(BN_SF * (accv + bd2[cl]), 0.f);
}

extern "C" void kernel_launch(void* const* d_in, const int* in_sizes, int n_in,
                              void* d_out, int out_size, void* d_ws, size_t ws_size,
                              hipStream_t stream) {
    const float* last_pos_rel = (const float*)d_in[1];
    const float* h0           = (const float*)d_in[2];
    const float* c0           = (const float*)d_in[3];
    const float* agent_type   = (const float*)d_in[6];  // at0 = first B elems
    const float* W_sp  = (const float*)d_in[8];
    const float* b_sp  = (const float*)d_in[9];
    const float* W_ih  = (const float*)d_in[10];
    const float* W_hh  = (const float*)d_in[11];
    const float* b_ih  = (const float*)d_in[12];
    const float* b_hh  = (const float*)d_in[13];
    const float* W_h2p = (const float*)d_in[14];
    const float* b_h2p = (const float*)d_in[15];
    const float* Wp_at = (const float*)d_in[20];
    const float* bp_at = (const float*)d_in[21];
    const float* Wm1   = (const float*)d_in[26];
    const float* bm1   = (const float*)d_in[27];
    const float* Wm2   = (const float*)d_in[28];
    const float* bm2   = (const float*)d_in[29];
    const float* Wd1   = (const float*)d_in[30];
    const float* bd1   = (const float*)d_in[31];
    const float* Wd2   = (const float*)d_in[32];
    const float* bd2   = (const float*)d_in[33];
    float* out = (float*)d_out;

    float* ws  = (float*)d_ws;
    float* hA   = ws;              // 131072  (LSTM h)
    float* hB   = hA + 131072;     // 131072  (dh / next h input)
    float* cbuf = hB + 131072;     // 131072
    float* di   = cbuf + 131072;   // 65536
    float* m1   = di + 65536;      // 524288
    float* ph   = m1 + 524288;     // 32768
    float* phW  = ph + 32768;      // 32768
    float* dh1  = phW + 32768;     // 1048576
    float* uv   = dh1 + 1048576;   // 1024

    hipMemcpyAsync(hB, h0, BB * HDD * sizeof(float), hipMemcpyDeviceToDevice, stream);
    hipMemcpyAsync(cbuf, c0, BB * HDD * sizeof(float), hipMemcpyDeviceToDevice, stream);
    k_uv<<<1, 512, 0, stream>>>(Wp_at, bp_at, Wm1, bm1, uv);
    k_di0<<<256, 256, 0, stream>>>(last_pos_rel, W_sp, b_sp, di);

    for (int t = 0; t < NSTEP; ++t) {
        k_lstm<<<256, 512, 0, stream>>>(W_ih, W_hh, b_ih, b_hh, W_h2p, b_h2p,
                                        W_sp, b_sp, Wm1, agent_type, uv,
                                        hB, cbuf, di, hA, m1, out + (size_t)t * BB * 2);
        k_m2max<<<dim3(8, 32), 512, 0, stream>>>(Wm2, bm2, m1, ph);
        k_phw<<<dim3(16, 4), 512, 0, stream>>>(Wd1, bd1, ph, phW);
        k_dh1<<<dim3(2, 128), 512, 0, stream>>>(Wd1, hA, phW, dh1);
        k_dh2<<<128, 1024, 0, stream>>>(Wd2, bd2, dh1, hB);
    }
    hipMemcpyAsync(out + NSTEP * BB * 2, hB, BB * HDD * sizeof(float),
                   hipMemcpyDeviceToDevice, stream);
}

// Round 2
// 919.604 us; speedup vs baseline: 1.7326x; 1.7326x over previous
//
#include <hip/hip_runtime.h>
#include <math.h>

#define BB    1024   // batch (G*P)
#define HDD   128    // h_dim
#define EE    64     // embedding dim
#define G4    512    // 4*HDD (gates / m1 width)
#define SCN   32     // scenes
#define PED   32     // peds per scene
#define MLPD  1024   // mlp_dim / bottleneck
#define NSTEP 12

#define BN_SF 0.9999950000374997f  /* 1/sqrt(1+1e-5) */

typedef __attribute__((ext_vector_type(8))) short short8v;
typedef __attribute__((ext_vector_type(4))) float float4v;

__device__ __forceinline__ float sigm(float x) { return 1.0f / (1.0f + expf(-x)); }

__device__ __forceinline__ short f2bf(float x) {
    unsigned u = __builtin_bit_cast(unsigned, x);
    unsigned r = (u + 0x7fffu + ((u >> 16) & 1u)) >> 16;
    return (short)r;
}

// ---- once: u[c], v[c] for the rank-1 agent-type contribution to m1 ----
__global__ void k_uv(const float* __restrict__ Wp_at, const float* __restrict__ bp_at,
                     const float* __restrict__ Wm1, const float* __restrict__ bm1,
                     float* __restrict__ uv) {
    __shared__ float rw[EE];
    int t = threadIdx.x;  // 512
    if (t < EE) {
        float s = 0.f;
        for (int k = 0; k < 6; ++k) s += Wp_at[k * EE + t];
        rw[t] = s;
    }
    __syncthreads();
    float u = 0.f, v = 0.f;
    for (int e = 0; e < EE; ++e) {
        float w = Wm1[(HDD + e) * G4 + t];
        u += rw[e] * w;
        v += bp_at[e] * w;
    }
    uv[t]      = 0.05f * u;
    uv[G4 + t] = 0.05f * v + bm1[t];
}

// ---- once: di0 = last_pos_rel @ W_sp + b_sp ----
__global__ void k_di0(const float* __restrict__ lpr, const float* __restrict__ W_sp,
                      const float* __restrict__ b_sp, float* __restrict__ di) {
    int i = blockIdx.x * blockDim.x + threadIdx.x;  // BB*EE
    if (i >= BB * EE) return;
    int r = i >> 6, c = i & 63;
    di[i] = lpr[r * 2] * W_sp[c] + lpr[r * 2 + 1] * W_sp[EE + c] + b_sp[c];
}

// ---- once: Wm2 f32 [512][1024] -> bf16 B-fragment layout ----
// dst[ntg(64)][kc(16)][lane(64)][j(8)] ; lane: n=ntg*16+(l&15), k=kc*32+(l>>4)*8+j
__global__ void k_cvt(const float* __restrict__ Wm2, short* __restrict__ Wm2s) {
    int i = blockIdx.x * blockDim.x + threadIdx.x;  // 512*1024
    int k = i >> 10, n = i & 1023;
    int ntg = n >> 4, kc = k >> 5;
    int lane = (n & 15) + (((k & 31) >> 3) << 4);
    int j = k & 7;
    Wm2s[ntg * 8192 + kc * 512 + lane * 8 + j] = f2bf(Wm2[i]);
}

// ---- per step: dh2(prev) + LSTM + rel + di_next + m1(bf16 frag) ; 4 rows/block ----
__global__ __launch_bounds__(512) void k_step(
    const float* __restrict__ W_ih, const float* __restrict__ W_hh,
    const float* __restrict__ b_ih, const float* __restrict__ b_hh,
    const float* __restrict__ W_h2p, const float* __restrict__ b_h2p,
    const float* __restrict__ W_sp, const float* __restrict__ b_sp,
    const float* __restrict__ Wm1, const float* __restrict__ at0,
    const float* __restrict__ uv,
    const float* __restrict__ Wd2, const float* __restrict__ bd2,
    const float* __restrict__ dh1, const float* __restrict__ h0,
    int first,
    float* __restrict__ cbuf, float* __restrict__ di,
    float* __restrict__ hA, short* __restrict__ m1s,
    float* __restrict__ outrel) {
    __shared__ float sdh1[4][MLPD];   // 16 KB
    __shared__ float sh[4][HDD];      // LSTM input h
    __shared__ float sdi[4][EE];
    __shared__ float sg[4][G4];
    __shared__ float shl[4][HDD];     // LSTM output h
    __shared__ float srel[4][2];
    int t = threadIdx.x;
    int row0 = blockIdx.x * 4;

    for (int i = t; i < 4 * EE; i += 512) sdi[i >> 6][i & 63] = di[row0 * EE + i];

    if (first) {
        for (int i = t; i < 4 * HDD; i += 512) sh[i >> 7][i & 127] = h0[row0 * HDD + i];
        __syncthreads();
    } else {
        for (int i = t; i < 4 * MLPD; i += 512) sdh1[i >> 10][i & 1023] = dh1[row0 * MLPD + i];
        __syncthreads();
        // h_prev = relu(BN*(dh1_prev @ Wd2 + bd2)) : 128 cols x 4 rows
        int r = t >> 7, col = t & 127;
        float a = bd2[col];
        const float* wp = Wd2 + col;
        const float* dr = sdh1[r];
        for (int k = 0; k < MLPD; ++k) a += dr[k] * wp[k * HDD];
        sh[r][col] = fmaxf(BN_SF * a, 0.f);
        __syncthreads();
    }

    // gates, column t, 4 rows
    float acc[4];
    {
        float b = b_ih[t] + b_hh[t];
#pragma unroll
        for (int r = 0; r < 4; ++r) acc[r] = b;
    }
    for (int k = 0; k < EE; ++k) {
        float w = W_ih[k * G4 + t];
#pragma unroll
        for (int r = 0; r < 4; ++r) acc[r] += sdi[r][k] * w;
    }
    for (int k = 0; k < HDD; ++k) {
        float w = W_hh[k * G4 + t];
#pragma unroll
        for (int r = 0; r < 4; ++r) acc[r] += sh[r][k] * w;
    }
#pragma unroll
    for (int r = 0; r < 4; ++r) sg[r][t] = acc[r];
    __syncthreads();

    // LSTM pointwise
    {
        int r = t >> 7, j = t & 127;
        int row = row0 + r;
        float gi = sg[r][j], gf = sg[r][j + HDD], gg = sg[r][j + 2 * HDD], go = sg[r][j + 3 * HDD];
        float cn = sigm(gf) * cbuf[row * HDD + j] + sigm(gi) * tanhf(gg);
        float hn = sigm(go) * tanhf(cn);
        cbuf[row * HDD + j] = cn;
        shl[r][j] = hn;
        hA[row * HDD + j] = hn;
    }
    __syncthreads();

    // rel = h @ W_h2p + b_h2p
    if (t < 8) {
        int r = t >> 1, d = t & 1;
        float s = b_h2p[d];
        for (int k = 0; k < HDD; ++k) s += shl[r][k] * W_h2p[k * 2 + d];
        srel[r][d] = s;
        outrel[(row0 + r) * 2 + d] = s;
    }
    __syncthreads();

    // di_next = rel @ W_sp + b_sp
    if (t < 256) {
        int r = t >> 6, cc = t & 63;
        di[(row0 + r) * EE + cc] = srel[r][0] * W_sp[cc] + srel[r][1] * W_sp[EE + cc] + b_sp[cc];
    }

    // m1 = relu(BN*(0.05*h@Wm1h + at0*u + v)) -> bf16 A-fragment layout
    float a[4] = {0.f, 0.f, 0.f, 0.f};
    for (int k = 0; k < HDD; ++k) {
        float w = Wm1[k * G4 + t];
#pragma unroll
        for (int r = 0; r < 4; ++r) a[r] += shl[r][k] * w;
    }
    float uc = uv[t], vc = uv[G4 + t];
    int scene = row0 >> 5;
    int mt = (row0 >> 4) & 1;
    int kc = t >> 5, j = t & 7;
    int klane = ((t & 31) >> 3) << 4;
#pragma unroll
    for (int r = 0; r < 4; ++r) {
        float pre = 0.05f * a[r] + at0[row0 + r] * uc + vc;
        float m1v = fmaxf(BN_SF * pre, 0.f);
        int lane = ((row0 + r) & 15) + klane;
        m1s[scene * 16384 + kc * 1024 + mt * 512 + lane * 8 + j] = f2bf(m1v);
    }
}

// ---- per step: m2 = m1 @ Wm2 (bf16 MFMA), per-scene colmax, bnrelu -> ph ----
// grid 128 = 32 scenes x 4 coltiles(256); 256 thr = 4 waves; wave: 32x64 tile
__global__ __launch_bounds__(256) void k_m2(const short* __restrict__ m1s,
                                            const short* __restrict__ Wm2s,
                                            const float* __restrict__ bm2,
                                            float* __restrict__ ph) {
    int t = threadIdx.x;
    int w = t >> 6, l = t & 63;
    int s = blockIdx.x >> 2, ct = blockIdx.x & 3;
    const short* ap = m1s + s * 16384 + l * 8;
    const short* bp = Wm2s + (ct * 16 + w * 4) * 8192 + l * 8;
    float4v acc[2][4] = {};
    for (int kc = 0; kc < 16; ++kc) {
        short8v a0 = *(const short8v*)(ap + kc * 1024);
        short8v a1 = *(const short8v*)(ap + kc * 1024 + 512);
#pragma unroll
        for (int nt = 0; nt < 4; ++nt) {
            short8v b = *(const short8v*)(bp + nt * 8192 + kc * 512);
            acc[0][nt] = __builtin_amdgcn_mfma_f32_16x16x32_bf16(a0, b, acc[0][nt], 0, 0, 0);
            acc[1][nt] = __builtin_amdgcn_mfma_f32_16x16x32_bf16(a1, b, acc[1][nt], 0, 0, 0);
        }
    }
#pragma unroll
    for (int nt = 0; nt < 4; ++nt) {
        float m = acc[0][nt][0];
#pragma unroll
        for (int ri = 1; ri < 4; ++ri) m = fmaxf(m, acc[0][nt][ri]);
#pragma unroll
        for (int ri = 0; ri < 4; ++ri) m = fmaxf(m, acc[1][nt][ri]);
        m = fmaxf(m, __shfl_xor(m, 16, 64));
        m = fmaxf(m, __shfl_xor(m, 32, 64));
        if (l < 16) {
            int col = ct * 256 + w * 64 + nt * 16 + l;
            ph[s * MLPD + col] = fmaxf(BN_SF * (m + bm2[col]), 0.f);
        }
    }
}

// ---- per step: phW = ph@Wd1p + bd1 (per scene) then dh1 = relu(BN*(h@Wd1h + phW)) ----
// grid 256 = 32 scenes x 8 coltiles(128); 256 thr = 128 cols x 2 (K-split / rowgroup)
__global__ __launch_bounds__(256) void k_pool2(const float* __restrict__ Wd1,
                                               const float* __restrict__ bd1,
                                               const float* __restrict__ ph,
                                               const float* __restrict__ hA,
                                               float* __restrict__ dh1) {
    __shared__ float sph[MLPD];        // 4 KB
    __shared__ float shh[PED][HDD];    // 16 KB
    __shared__ float spw[2][128];
    int t = threadIdx.x;
    int s = blockIdx.x >> 3, ct = blockIdx.x & 7;
    for (int i = t; i < MLPD; i += 256) sph[i] = ph[s * MLPD + i];
    for (int i = t; i < PED * HDD; i += 256) shh[i >> 7][i & 127] = hA[s * PED * HDD + i];
    __syncthreads();
    int col = t & 127, half = t >> 7;
    int cc = ct * 128 + col;
    // phW: split-K over 2 halves
    {
        const float* wp = Wd1 + (HDD + half * 512) * MLPD + cc;
        float a = half ? 0.f : bd1[cc];
        for (int k = 0; k < 512; ++k) a += sph[half * 512 + k] * wp[k * MLPD];
        spw[half][col] = a;
    }
    __syncthreads();
    float pw = spw[0][col] + spw[1][col];
    // dh1: 16 rows per thread, K=128
    float accr[16] = {0.f, 0.f, 0.f, 0.f, 0.f, 0.f, 0.f, 0.f,
                      0.f, 0.f, 0.f, 0.f, 0.f, 0.f, 0.f, 0.f};
    const float* wh = Wd1 + cc;
    for (int k = 0; k < HDD; ++k) {
        float w = wh[k * MLPD];
#pragma unroll
        for (int r = 0; r < 16; ++r) accr[r] += shh[half * 16 + r][k] * w;
    }
#pragma unroll
    for (int r = 0; r < 16; ++r)
        dh1[(s * PED + half * 16 + r) * MLPD + cc] = fmaxf(BN_SF * (accr[r] + pw), 0.f);
}

// ---- final: h = relu(BN*(dh1 @ Wd2 + bd2)) -> out ----
__global__ __launch_bounds__(512) void k_hfin(const float* __restrict__ Wd2,
                                              const float* __restrict__ bd2,
                                              const float* __restrict__ dh1,
                                              float* __restrict__ outh) {
    __shared__ float sdh1[4][MLPD];
    int t = threadIdx.x;
    int row0 = blockIdx.x * 4;
    for (int i = t; i < 4 * MLPD; i += 512) sdh1[i >> 10][i & 1023] = dh1[row0 * MLPD + i];
    __syncthreads();
    int r = t >> 7, col = t & 127;
    float a = bd2[col];
    const float* wp = Wd2 + col;
    const float* dr = sdh1[r];
    for (int k = 0; k < MLPD; ++k) a += dr[k] * wp[k * HDD];
    outh[(row0 + r) * HDD + col] = fmaxf(BN_SF * a, 0.f);
}

extern "C" void kernel_launch(void* const* d_in, const int* in_sizes, int n_in,
                              void* d_out, int out_size, void* d_ws, size_t ws_size,
                              hipStream_t stream) {
    const float* last_pos_rel = (const float*)d_in[1];
    const float* h0           = (const float*)d_in[2];
    const float* c0           = (const float*)d_in[3];
    const float* agent_type   = (const float*)d_in[6];  // at0 = first B elems
    const float* W_sp  = (const float*)d_in[8];
    const float* b_sp  = (const float*)d_in[9];
    const float* W_ih  = (const float*)d_in[10];
    const float* W_hh  = (const float*)d_in[11];
    const float* b_ih  = (const float*)d_in[12];
    const float* b_hh  = (const float*)d_in[13];
    const float* W_h2p = (const float*)d_in[14];
    const float* b_h2p = (const float*)d_in[15];
    const float* Wp_at = (const float*)d_in[20];
    const float* bp_at = (const float*)d_in[21];
    const float* Wm1   = (const float*)d_in[26];
    const float* bm1   = (const float*)d_in[27];
    const float* Wm2   = (const float*)d_in[28];
    const float* bm2   = (const float*)d_in[29];
    const float* Wd1   = (const float*)d_in[30];
    const float* bd1   = (const float*)d_in[31];
    const float* Wd2   = (const float*)d_in[32];
    const float* bd2   = (const float*)d_in[33];
    float* out = (float*)d_out;

    float* ws   = (float*)d_ws;
    float* hA   = ws;              // 131072
    float* cbuf = hA + 131072;     // 131072
    float* di   = cbuf + 131072;   // 65536
    float* ph   = di + 65536;      // 32768
    float* dh1  = ph + 32768;      // 1048576
    float* uv   = dh1 + 1048576;   // 1024
    short* m1s  = (short*)(uv + 1024);        // 524288 shorts (1 MB)
    short* Wm2s = m1s + 524288;               // 524288 shorts (1 MB)

    hipMemcpyAsync(cbuf, c0, BB * HDD * sizeof(float), hipMemcpyDeviceToDevice, stream);
    k_cvt<<<1024, 512, 0, stream>>>(Wm2, Wm2s);
    k_uv<<<1, 512, 0, stream>>>(Wp_at, bp_at, Wm1, bm1, uv);
    k_di0<<<256, 256, 0, stream>>>(last_pos_rel, W_sp, b_sp, di);

    for (int t = 0; t < NSTEP; ++t) {
        k_step<<<256, 512, 0, stream>>>(W_ih, W_hh, b_ih, b_hh, W_h2p, b_h2p,
                                        W_sp, b_sp, Wm1, agent_type, uv,
                                        Wd2, bd2, dh1, h0, (t == 0) ? 1 : 0,
                                        cbuf, di, hA, m1s, out + (size_t)t * BB * 2);
        k_m2<<<128, 256, 0, stream>>>(m1s, Wm2s, bm2, ph);
        k_pool2<<<256, 256, 0, stream>>>(Wd1, bd1, ph, hA, dh1);
    }
    k_hfin<<<256, 512, 0, stream>>>(Wd2, bd2, dh1, out + NSTEP * BB * 2);
}

// Round 3
// 422.716 us; speedup vs baseline: 3.7693x; 2.1755x over previous
//
#include <hip/hip_runtime.h>
#include <math.h>

#define BB    1024
#define HDD   128
#define EE    64
#define G4    512
#define SCN   32
#define PED   32
#define MLPD  1024
#define NSTEP 12

#define BN_SF 0.9999950000374997f  /* 1/sqrt(1+1e-5) */

typedef __attribute__((ext_vector_type(8))) short short8v;
typedef __attribute__((ext_vector_type(4))) float float4v;

__device__ __forceinline__ float sigm(float x) { return 1.0f / (1.0f + expf(-x)); }

__device__ __forceinline__ short f2bf(float x) {
    unsigned u = __builtin_bit_cast(unsigned, x);
    unsigned r = (u + 0x7fffu + ((u >> 16) & 1u)) >> 16;
    return (short)r;
}
__device__ __forceinline__ float bf2f(short h) {
    unsigned u = ((unsigned)(unsigned short)h) << 16;
    return __builtin_bit_cast(float, u);
}

// ---- once: u[c], v[c] rank-1 agent-type contribution to m1 (0.05 folded) ----
__global__ void k_uv(const float* __restrict__ Wp_at, const float* __restrict__ bp_at,
                     const float* __restrict__ Wm1, const float* __restrict__ bm1,
                     float* __restrict__ uv) {
    __shared__ float rw[EE];
    int t = threadIdx.x;  // 512
    if (t < EE) {
        float s = 0.f;
        for (int k = 0; k < 6; ++k) s += Wp_at[k * EE + t];
        rw[t] = s;
    }
    __syncthreads();
    float u = 0.f, v = 0.f;
    for (int e = 0; e < EE; ++e) {
        float w = Wm1[(HDD + e) * G4 + t];
        u += rw[e] * w;
        v += bp_at[e] * w;
    }
    uv[t]      = 0.05f * u;
    uv[G4 + t] = 0.05f * v + bm1[t];
}

// ---- once: di0 = last_pos_rel @ W_sp + b_sp ----
__global__ void k_di0(const float* __restrict__ lpr, const float* __restrict__ W_sp,
                      const float* __restrict__ b_sp, float* __restrict__ di) {
    int i = blockIdx.x * blockDim.x + threadIdx.x;
    if (i >= BB * EE) return;
    int r = i >> 6, c = i & 63;
    di[i] = lpr[r * 2] * W_sp[c] + lpr[r * 2 + 1] * W_sp[EE + c] + b_sp[c];
}

// ---- once: Wm2 f32 [512][1024] -> bf16 B-fragment layout (16x16x32) ----
__global__ void k_cvt(const float* __restrict__ Wm2, short* __restrict__ Wm2s) {
    int i = blockIdx.x * blockDim.x + threadIdx.x;  // 512*1024
    int k = i >> 10, n = i & 1023;
    int ntg = n >> 4, kc = k >> 5;
    int lane = (n & 15) + (((k & 31) >> 3) << 4);
    int j = k & 7;
    Wm2s[ntg * 8192 + kc * 512 + lane * 8 + j] = f2bf(Wm2[i]);
}

// ---- once: generic f32 [K][N] -> bf16 B-fragment layout ----
__global__ void k_cvtB(const float* __restrict__ src, short* __restrict__ dst,
                       int K, int N, float scale) {
    int i = blockIdx.x * 256 + threadIdx.x;
    if (i >= K * N) return;
    int k = i / N, n = i - k * N;
    int kcn = K >> 5;
    size_t d = (size_t)(n >> 4) * kcn * 512 + (size_t)(k >> 5) * 512
             + (size_t)(((n & 15) + (((k & 31) >> 3) << 4)) << 3) + (k & 7);
    dst[d] = f2bf(scale * src[i]);
}

// ---- once: Wg = [W_ih; W_hh] [192][512] -> hi/lo bf16 B-fragments ----
__global__ void k_cvtg(const float* __restrict__ Wih, const float* __restrict__ Whh,
                       short* __restrict__ dhi, short* __restrict__ dlo) {
    int i = blockIdx.x * 256 + threadIdx.x;  // 192*512
    int k = i >> 9, n = i & 511;
    float v = (k < 64) ? Wih[k * 512 + n] : Whh[(k - 64) * 512 + n];
    short hi = f2bf(v);
    short lo = f2bf(v - bf2f(hi));
    size_t d = (size_t)(n >> 4) * 6 * 512 + (size_t)(k >> 5) * 512
             + (size_t)(((n & 15) + (((k & 31) >> 3) << 4)) << 3) + (k & 7);
    dhi[d] = hi; dlo[d] = lo;
}

// ---- per step: dh2(prev, MFMA) + LSTM(hi/lo MFMA) + rel + di + m1(MFMA) ----
// grid 64 blocks x 512 thr (8 waves); block b: 16 rows r0=b*16, scene b>>1, mt b&1
__global__ __launch_bounds__(512) void k_step(
    const short* __restrict__ WgHi, const short* __restrict__ WgLo,
    const short* __restrict__ Wm1f, const short* __restrict__ Wd2f,
    const float* __restrict__ bih, const float* __restrict__ bhh,
    const float* __restrict__ Whp, const float* __restrict__ bhp,
    const float* __restrict__ Wsp, const float* __restrict__ bsp,
    const float* __restrict__ bd2, const float* __restrict__ at0,
    const float* __restrict__ uv, const float* __restrict__ h0,
    const short* __restrict__ dh1f, int first,
    float* __restrict__ cbuf, float* __restrict__ di,
    float* __restrict__ hA, short* __restrict__ m1s,
    float* __restrict__ outrel) {
    __shared__ float sh[16][HDD];
    __shared__ float sg[16][G4];
    __shared__ float sdi[16][EE];
    __shared__ short xfh[6 * 512];
    __shared__ short xfl[6 * 512];
    __shared__ short xm[4 * 512];
    __shared__ float sat[16];
    __shared__ float srel[16][2];
    int t = threadIdx.x, b = blockIdx.x;
    int l = t & 63, w = t >> 6;
    int r0 = b * 16;

    // dh2 MFMA: h_in = relu(BN*(dh1_prev @ Wd2 + bd2)); wave w = n-frag w
    float4v hacc = {0.f, 0.f, 0.f, 0.f};
    if (!first) {
        const short* ap = dh1f + (size_t)b * 16384 + l * 8;
        const short* bp = Wd2f + (size_t)w * 16384 + l * 8;
        for (int kc = 0; kc < 32; ++kc) {
            short8v a  = *(const short8v*)(ap + kc * 512);
            short8v bb = *(const short8v*)(bp + kc * 512);
            hacc = __builtin_amdgcn_mfma_f32_16x16x32_bf16(a, bb, hacc, 0, 0, 0);
        }
    }
    for (int i = t; i < 16 * EE; i += 512) sdi[i >> 6][i & 63] = di[r0 * EE + i];
    if (t < 16) sat[t] = at0[r0 + t];
    if (first) {
        for (int i = t; i < 16 * HDD; i += 512) sh[i >> 7][i & 127] = h0[r0 * HDD + i];
    } else {
        int col = w * 16 + (l & 15);
        float bb2 = bd2[col];
#pragma unroll
        for (int r = 0; r < 4; ++r) {
            int row = ((l >> 4) << 2) + r;
            sh[row][col] = fmaxf(BN_SF * (hacc[r] + bb2), 0.f);
        }
    }
    __syncthreads();

    // build X=[di|h] hi/lo A-fragments
    for (int i = t; i < 6 * 512; i += 512) {
        int pos = i & 511, kc = i >> 9;
        int ll = pos >> 3, j = pos & 7;
        int row = ll & 15, k = kc * 32 + ((ll >> 4) << 3) + j;
        float v = (k < 64) ? sdi[row][k] : sh[row][k - 64];
        short hi = f2bf(v);
        xfh[i] = hi;
        xfl[i] = f2bf(v - bf2f(hi));
    }
    __syncthreads();

    // gates MFMA (hi/lo x hi/lo, 3 terms): wave w -> n-frags w*4..w*4+3
    {
        float4v ga[4] = {{0,0,0,0},{0,0,0,0},{0,0,0,0},{0,0,0,0}};
        for (int kc = 0; kc < 6; ++kc) {
            short8v ah = *(const short8v*)(&xfh[kc * 512 + l * 8]);
            short8v al = *(const short8v*)(&xfl[kc * 512 + l * 8]);
#pragma unroll
            for (int q = 0; q < 4; ++q) {
                int nf = w * 4 + q;
                short8v bh = *(const short8v*)(WgHi + (size_t)nf * 3072 + kc * 512 + l * 8);
                short8v bl = *(const short8v*)(WgLo + (size_t)nf * 3072 + kc * 512 + l * 8);
                ga[q] = __builtin_amdgcn_mfma_f32_16x16x32_bf16(ah, bh, ga[q], 0, 0, 0);
                ga[q] = __builtin_amdgcn_mfma_f32_16x16x32_bf16(ah, bl, ga[q], 0, 0, 0);
                ga[q] = __builtin_amdgcn_mfma_f32_16x16x32_bf16(al, bh, ga[q], 0, 0, 0);
            }
        }
#pragma unroll
        for (int q = 0; q < 4; ++q) {
            int col = (w * 4 + q) * 16 + (l & 15);
            float bb = bih[col] + bhh[col];
#pragma unroll
            for (int r = 0; r < 4; ++r) {
                int row = ((l >> 4) << 2) + r;
                sg[row][col] = ga[q][r] + bb;
            }
        }
    }
    __syncthreads();

    // LSTM pointwise (overwrites sh with new h)
    for (int i = t; i < 16 * HDD; i += 512) {
        int row = i >> 7, j = i & 127;
        float gi = sg[row][j], gf = sg[row][j + 128], gg = sg[row][j + 256], go = sg[row][j + 384];
        float cn = sigm(gf) * cbuf[(r0 + row) * HDD + j] + sigm(gi) * tanhf(gg);
        float hn = sigm(go) * tanhf(cn);
        cbuf[(r0 + row) * HDD + j] = cn;
        sh[row][j] = hn;
        hA[(r0 + row) * HDD + j] = hn;
    }
    __syncthreads();

    // rel (f32, exact -> output)
    if (t < 32) {
        int row = t >> 1, d = t & 1;
        float s2 = bhp[d];
        for (int k = 0; k < HDD; ++k) s2 += sh[row][k] * Whp[k * 2 + d];
        srel[row][d] = s2;
        outrel[(r0 + row) * 2 + d] = s2;
    }
    // new-h bf16 A-fragments for m1
    for (int i = t; i < 4 * 512; i += 512) {
        int pos = i & 511, kc = i >> 9;
        int ll = pos >> 3, j = pos & 7;
        int row = ll & 15, k = kc * 32 + ((ll >> 4) << 3) + j;
        xm[i] = f2bf(sh[row][k]);
    }
    __syncthreads();

    // di_next
    for (int i = t; i < 16 * EE; i += 512) {
        int row = i >> 6, c = i & 63;
        di[(r0 + row) * EE + c] = srel[row][0] * Wsp[c] + srel[row][1] * Wsp[EE + c] + bsp[c];
    }

    // m1 MFMA -> bf16 A-fragments for k_m2
    {
        float4v ma[4] = {{0,0,0,0},{0,0,0,0},{0,0,0,0},{0,0,0,0}};
        for (int kc = 0; kc < 4; ++kc) {
            short8v a = *(const short8v*)(&xm[kc * 512 + l * 8]);
#pragma unroll
            for (int q = 0; q < 4; ++q) {
                int nf = w * 4 + q;
                short8v bb = *(const short8v*)(Wm1f + (size_t)nf * 2048 + kc * 512 + l * 8);
                ma[q] = __builtin_amdgcn_mfma_f32_16x16x32_bf16(a, bb, ma[q], 0, 0, 0);
            }
        }
        int s = b >> 1, mt = b & 1;
#pragma unroll
        for (int q = 0; q < 4; ++q) {
            int col = (w * 4 + q) * 16 + (l & 15);
            float uc = uv[col], vc = uv[G4 + col];
#pragma unroll
            for (int r = 0; r < 4; ++r) {
                int rowC = ((l >> 4) << 2) + r;
                float pre = ma[q][r] + sat[rowC] * uc + vc;
                float m1v = fmaxf(BN_SF * pre, 0.f);
                int kcD = col >> 5;
                int laneD = rowC + (((col & 31) >> 3) << 4);
                m1s[(size_t)s * 16384 + kcD * 1024 + mt * 512 + laneD * 8 + (col & 7)] = f2bf(m1v);
            }
        }
    }
}

// ---- per step: m2 = m1 @ Wm2 (MFMA), per-scene colmax, bnrelu -> ph ----
__global__ __launch_bounds__(256) void k_m2(const short* __restrict__ m1s,
                                            const short* __restrict__ Wm2s,
                                            const float* __restrict__ bm2,
                                            float* __restrict__ ph) {
    int t = threadIdx.x;
    int w = t >> 6, l = t & 63;
    int s = blockIdx.x >> 2, ct = blockIdx.x & 3;
    const short* ap = m1s + s * 16384 + l * 8;
    const short* bp = Wm2s + (ct * 16 + w * 4) * 8192 + l * 8;
    float4v acc[2][4] = {};
    for (int kc = 0; kc < 16; ++kc) {
        short8v a0 = *(const short8v*)(ap + kc * 1024);
        short8v a1 = *(const short8v*)(ap + kc * 1024 + 512);
#pragma unroll
        for (int nt = 0; nt < 4; ++nt) {
            short8v b = *(const short8v*)(bp + nt * 8192 + kc * 512);
            acc[0][nt] = __builtin_amdgcn_mfma_f32_16x16x32_bf16(a0, b, acc[0][nt], 0, 0, 0);
            acc[1][nt] = __builtin_amdgcn_mfma_f32_16x16x32_bf16(a1, b, acc[1][nt], 0, 0, 0);
        }
    }
#pragma unroll
    for (int nt = 0; nt < 4; ++nt) {
        float m = acc[0][nt][0];
#pragma unroll
        for (int ri = 1; ri < 4; ++ri) m = fmaxf(m, acc[0][nt][ri]);
#pragma unroll
        for (int ri = 0; ri < 4; ++ri) m = fmaxf(m, acc[1][nt][ri]);
        m = fmaxf(m, __shfl_xor(m, 16, 64));
        m = fmaxf(m, __shfl_xor(m, 32, 64));
        if (l < 16) {
            int col = ct * 256 + w * 64 + nt * 16 + l;
            ph[s * MLPD + col] = fmaxf(BN_SF * (m + bm2[col]), 0.f);
        }
    }
}

// ---- per step: phw (broadcast-A MFMA) + dh1h MFMA -> dh1f bf16 A-fragments ----
// grid 256 = 32 scenes x 8 coltiles(128); 256 thr = 4 waves
__global__ __launch_bounds__(256) void k_pool2(const short* __restrict__ Wd1f,
                                               const float* __restrict__ bd1,
                                               const float* __restrict__ ph,
                                               const float* __restrict__ hA,
                                               short* __restrict__ dh1f) {
    __shared__ short sphb[1024];
    __shared__ short shf[2][2048];
    int t = threadIdx.x, l = t & 63, w = t >> 6;
    int s = blockIdx.x >> 3, ct = blockIdx.x & 7;
    for (int i = t; i < 1024; i += 256) sphb[i] = f2bf(ph[s * MLPD + i]);
    for (int i = t; i < 4096; i += 256) {
        int mt = i >> 11, pos = i & 2047;
        int kc = pos >> 9, ll = (pos >> 3) & 63, j = pos & 7;
        int row = ll & 15, k = kc * 32 + ((ll >> 4) << 3) + j;
        shf[mt][pos] = f2bf(hA[(s * PED + mt * 16 + row) * HDD + k]);
    }
    __syncthreads();
    float4v accp[2], acch[2][2];
#pragma unroll
    for (int q = 0; q < 2; ++q) {
        int col = ct * 128 + (w * 2 + q) * 16 + (l & 15);
        float bb = bd1[col];
        accp[q] = (float4v){bb, bb, bb, bb};
        acch[q][0] = (float4v){0.f, 0.f, 0.f, 0.f};
        acch[q][1] = (float4v){0.f, 0.f, 0.f, 0.f};
    }
    // ph part: all 16 A-rows = ph -> every row of accp identical
    for (int kc = 0; kc < 32; ++kc) {
        short8v a = *(const short8v*)(&sphb[kc * 32 + ((l >> 4) << 3)]);
#pragma unroll
        for (int q = 0; q < 2; ++q) {
            int nt = ct * 8 + w * 2 + q;
            short8v bb = *(const short8v*)(Wd1f + (size_t)nt * 18432 + (size_t)(4 + kc) * 512 + l * 8);
            accp[q] = __builtin_amdgcn_mfma_f32_16x16x32_bf16(a, bb, accp[q], 0, 0, 0);
        }
    }
    // h part
    for (int kc = 0; kc < 4; ++kc) {
        short8v a0 = *(const short8v*)(&shf[0][kc * 512 + l * 8]);
        short8v a1 = *(const short8v*)(&shf[1][kc * 512 + l * 8]);
#pragma unroll
        for (int q = 0; q < 2; ++q) {
            int nt = ct * 8 + w * 2 + q;
            short8v bb = *(const short8v*)(Wd1f + (size_t)nt * 18432 + (size_t)kc * 512 + l * 8);
            acch[q][0] = __builtin_amdgcn_mfma_f32_16x16x32_bf16(a0, bb, acch[q][0], 0, 0, 0);
            acch[q][1] = __builtin_amdgcn_mfma_f32_16x16x32_bf16(a1, bb, acch[q][1], 0, 0, 0);
        }
    }
#pragma unroll
    for (int q = 0; q < 2; ++q) {
        int col = ct * 128 + (w * 2 + q) * 16 + (l & 15);
        int kcD = col >> 5, j = col & 7;
        int lhi = ((col & 31) >> 3) << 4;
#pragma unroll
        for (int mt = 0; mt < 2; ++mt) {
#pragma unroll
            for (int r = 0; r < 4; ++r) {
                int rowC = ((l >> 4) << 2) + r;
                float v = fmaxf(BN_SF * (acch[q][mt][r] + accp[q][r]), 0.f);
                dh1f[(size_t)(s * 2 + mt) * 16384 + (size_t)kcD * 512 + (rowC + lhi) * 8 + j] = f2bf(v);
            }
        }
    }
}

// ---- final: h = relu(BN*(dh1 @ Wd2 + bd2)) -> out (MFMA) ----
__global__ __launch_bounds__(512) void k_hfin2(const short* __restrict__ Wd2f,
                                               const float* __restrict__ bd2,
                                               const short* __restrict__ dh1f,
                                               float* __restrict__ outh) {
    int t = threadIdx.x, l = t & 63, w = t >> 6, b = blockIdx.x;
    float4v acc = {0.f, 0.f, 0.f, 0.f};
    const short* ap = dh1f + (size_t)b * 16384 + l * 8;
    const short* bp = Wd2f + (size_t)w * 16384 + l * 8;
    for (int kc = 0; kc < 32; ++kc) {
        short8v a  = *(const short8v*)(ap + kc * 512);
        short8v bb = *(const short8v*)(bp + kc * 512);
        acc = __builtin_amdgcn_mfma_f32_16x16x32_bf16(a, bb, acc, 0, 0, 0);
    }
    int col = w * 16 + (l & 15);
    float bb2 = bd2[col];
#pragma unroll
    for (int r = 0; r < 4; ++r) {
        int row = ((l >> 4) << 2) + r;
        outh[(b * 16 + row) * HDD + col] = fmaxf(BN_SF * (acc[r] + bb2), 0.f);
    }
}

extern "C" void kernel_launch(void* const* d_in, const int* in_sizes, int n_in,
                              void* d_out, int out_size, void* d_ws, size_t ws_size,
                              hipStream_t stream) {
    const float* last_pos_rel = (const float*)d_in[1];
    const float* h0           = (const float*)d_in[2];
    const float* c0           = (const float*)d_in[3];
    const float* agent_type   = (const float*)d_in[6];
    const float* W_sp  = (const float*)d_in[8];
    const float* b_sp  = (const float*)d_in[9];
    const float* W_ih  = (const float*)d_in[10];
    const float* W_hh  = (const float*)d_in[11];
    const float* b_ih  = (const float*)d_in[12];
    const float* b_hh  = (const float*)d_in[13];
    const float* W_h2p = (const float*)d_in[14];
    const float* b_h2p = (const float*)d_in[15];
    const float* Wp_at = (const float*)d_in[20];
    const float* bp_at = (const float*)d_in[21];
    const float* Wm1   = (const float*)d_in[26];
    const float* bm1   = (const float*)d_in[27];
    const float* Wm2   = (const float*)d_in[28];
    const float* bm2   = (const float*)d_in[29];
    const float* Wd1   = (const float*)d_in[30];
    const float* bd1   = (const float*)d_in[31];
    const float* Wd2   = (const float*)d_in[32];
    const float* bd2   = (const float*)d_in[33];
    float* out = (float*)d_out;

    float* ws   = (float*)d_ws;
    float* hA   = ws;              // 131072 f
    float* cbuf = hA + 131072;     // 131072 f
    float* di   = cbuf + 131072;   // 65536 f
    float* ph   = di + 65536;      // 32768 f
    float* uv   = ph + 32768;      // 1024 f
    short* m1s  = (short*)(uv + 1024);   // 524288 sh
    short* Wm2s = m1s + 524288;          // 524288 sh
    short* dh1f = Wm2s + 524288;         // 1048576 sh
    short* WgHi = dh1f + 1048576;        // 98304 sh
    short* WgLo = WgHi + 98304;          // 98304 sh
    short* Wm1f = WgLo + 98304;          // 65536 sh
    short* Wd1f = Wm1f + 65536;          // 1179648 sh
    short* Wd2f = Wd1f + 1179648;        // 131072 sh

    hipMemcpyAsync(cbuf, c0, BB * HDD * sizeof(float), hipMemcpyDeviceToDevice, stream);
    k_cvt<<<1024, 512, 0, stream>>>(Wm2, Wm2s);
    k_cvtg<<<384, 256, 0, stream>>>(W_ih, W_hh, WgHi, WgLo);
    k_cvtB<<<256, 256, 0, stream>>>(Wm1, Wm1f, 128, 512, 0.05f);
    k_cvtB<<<4608, 256, 0, stream>>>(Wd1, Wd1f, 1152, 1024, 1.0f);
    k_cvtB<<<512, 256, 0, stream>>>(Wd2, Wd2f, 1024, 128, 1.0f);
    k_uv<<<1, 512, 0, stream>>>(Wp_at, bp_at, Wm1, bm1, uv);
    k_di0<<<256, 256, 0, stream>>>(last_pos_rel, W_sp, b_sp, di);

    for (int t = 0; t < NSTEP; ++t) {
        k_step<<<64, 512, 0, stream>>>(WgHi, WgLo, Wm1f, Wd2f,
                                       b_ih, b_hh, W_h2p, b_h2p, W_sp, b_sp,
                                       bd2, agent_type, uv, h0, dh1f, (t == 0) ? 1 : 0,
                                       cbuf, di, hA, m1s, out + (size_t)t * BB * 2);
        k_m2<<<128, 256, 0, stream>>>(m1s, Wm2s, bm2, ph);
        k_pool2<<<256, 256, 0, stream>>>(Wd1f, bd1, ph, hA, dh1f);
    }
    k_hfin2<<<64, 512, 0, stream>>>(Wd2f, bd2, dh1f, out + NSTEP * BB * 2);
}